// Round 13
// baseline (320.877 us; speedup 1.0000x reference)
//
#include <hip/hip_runtime.h>

// fp16 vector types for MFMA fragments
typedef _Float16 hf2 __attribute__((ext_vector_type(2)));
typedef _Float16 hf4 __attribute__((ext_vector_type(4)));
typedef _Float16 hf8 __attribute__((ext_vector_type(8)));
typedef float    fx4 __attribute__((ext_vector_type(4)));

// async global->LDS, 16B per lane; LDS dest must be lane-linear (base + lane*16)
#define GLD16(gp, lp) __builtin_amdgcn_global_load_lds(                      \
    (const __attribute__((address_space(1))) void*)(gp),                     \
    (__attribute__((address_space(3))) void*)(lp), 16, 0, 0)

// ---------------- f32 -> f16 conversion ----------------
__global__ __launch_bounds__(256) void cvt_x_k(const float* __restrict__ s,
                                               _Float16* __restrict__ d) {
  size_t i = (size_t)blockIdx.x * 256 + threadIdx.x;  // grid 4096 -> 1,048,576 float4s
  float4 v = ((const float4*)s)[i];
  hf4 o = {(_Float16)v.x, (_Float16)v.y, (_Float16)v.z, (_Float16)v.w};
  *(hf4*)(d + 4 * i) = o;
}

__global__ __launch_bounds__(256) void cvt_w_k(const float* __restrict__ s0,
                                               const float* __restrict__ s1,
                                               const float* __restrict__ s2,
                                               const float* __restrict__ s3,
                                               _Float16* __restrict__ d) {
  const float* s = blockIdx.y == 0 ? s0 : blockIdx.y == 1 ? s1 : blockIdx.y == 2 ? s2 : s3;
  size_t i = (size_t)blockIdx.x * 256 + threadIdx.x;  // grid.x 1024 -> 262,144 float4s
  float4 v = ((const float4*)s)[i];
  hf4 o = {(_Float16)v.x, (_Float16)v.y, (_Float16)v.z, (_Float16)v.w};
  *(hf4*)(d + (size_t)blockIdx.y * 1048576 + 4 * i) = o;
}

// ---------------- 128x128 tile GEMM, C = A[M,1024] * B[N,1024]^T + bias ----------------
__device__ __forceinline__ void gemm_tile(
    const _Float16* __restrict__ A, const _Float16* __restrict__ B,
    const float* __restrict__ bias, _Float16* __restrict__ Ch,
    float* __restrict__ Cf, int m0, int n0, int ldc, int mode)
{
  __shared__ alignas(16) _Float16 Asm[2][128 * 32];
  __shared__ alignas(16) _Float16 Bsm[2][128 * 32];
  const int tid = (int)threadIdx.x;
  const int lane = tid & 63, wv = tid >> 6;
  const int col = lane & 15, g = lane >> 4;

  fx4 acc[2][8];
#pragma unroll
  for (int i = 0; i < 2; ++i)
#pragma unroll
    for (int j = 0; j < 8; ++j) acc[i][j] = fx4{0.f, 0.f, 0.f, 0.f};

  const int cp0 = tid, cp1 = tid + 256;
  const int row0 = cp0 >> 2, row1 = cp1 >> 2;
  const int ch0 = (cp0 & 3) ^ ((row0 >> 1) & 3);
  const int ch1 = (cp1 & 3) ^ ((row1 >> 1) & 3);
  const _Float16* a0 = A + (size_t)(m0 + row0) * 1024 + ch0 * 8;
  const _Float16* a1 = A + (size_t)(m0 + row1) * 1024 + ch1 * 8;
  const _Float16* b0 = B + (size_t)(n0 + row0) * 1024 + ch0 * 8;
  const _Float16* b1 = B + (size_t)(n0 + row1) * 1024 + ch1 * 8;

  int aoff[2], boff[8];
#pragma unroll
  for (int mi = 0; mi < 2; ++mi) {
    int row = wv * 32 + mi * 16 + col;
    aoff[mi] = (row * 4 + (g ^ ((row >> 1) & 3))) * 8;
  }
#pragma unroll
  for (int nj = 0; nj < 8; ++nj) {
    int row = nj * 16 + col;
    boff[nj] = (row * 4 + (g ^ ((row >> 1) & 3))) * 8;
  }

#define STAGE_T(bufi, kt) {                          \
    GLD16(a0 + (kt) * 32, &Asm[bufi][cp0 * 8]);      \
    GLD16(a1 + (kt) * 32, &Asm[bufi][cp1 * 8]);      \
    GLD16(b0 + (kt) * 32, &Bsm[bufi][cp0 * 8]);      \
    GLD16(b1 + (kt) * 32, &Bsm[bufi][cp1 * 8]); }

  STAGE_T(0, 0);
  int buf = 0;
  for (int kt = 0; kt < 32; ++kt) {
    __syncthreads();
    if (kt + 1 < 32) STAGE_T(buf ^ 1, kt + 1);
    hf8 af[2], bf[8];
#pragma unroll
    for (int mi = 0; mi < 2; ++mi) af[mi] = *(const hf8*)&Asm[buf][aoff[mi]];
#pragma unroll
    for (int nj = 0; nj < 8; ++nj) bf[nj] = *(const hf8*)&Bsm[buf][boff[nj]];
#pragma unroll
    for (int mi = 0; mi < 2; ++mi)
#pragma unroll
      for (int nj = 0; nj < 8; ++nj)
        acc[mi][nj] = __builtin_amdgcn_mfma_f32_16x16x32_f16(af[mi], bf[nj], acc[mi][nj], 0, 0, 0);
    buf ^= 1;
  }
#undef STAGE_T

  if (mode == 2) {
#pragma unroll
    for (int nj = 0; nj < 8; ++nj) {
      float bn = bias[n0 + nj * 16 + col];
#pragma unroll
      for (int mi = 0; mi < 2; ++mi)
#pragma unroll
        for (int r = 0; r < 4; ++r)
          Cf[(size_t)(m0 + wv * 32 + mi * 16 + 4 * g + r) * ldc + n0 + nj * 16 + col] =
              acc[mi][nj][r] + bn;
    }
  } else if (mode == 0) {
#pragma unroll
    for (int nj = 0; nj < 8; ++nj) {
      float bn = bias[n0 + nj * 16 + col];
#pragma unroll
      for (int mi = 0; mi < 2; ++mi)
#pragma unroll
        for (int r = 0; r < 4; ++r)
          Ch[(size_t)(m0 + wv * 32 + mi * 16 + 4 * g + r) * ldc + n0 + nj * 16 + col] =
              (_Float16)(acc[mi][nj][r] + bn);
    }
  } else {  // mode 1: bias over m
#pragma unroll
    for (int mi = 0; mi < 2; ++mi)
#pragma unroll
      for (int r = 0; r < 4; ++r) {
        float bm = bias[m0 + wv * 32 + mi * 16 + 4 * g + r];
#pragma unroll
        for (int nj = 0; nj < 8; ++nj)
          Ch[(size_t)(m0 + wv * 32 + mi * 16 + 4 * g + r) * ldc + n0 + nj * 16 + col] =
              (_Float16)(acc[mi][nj][r] + bm);
      }
  }
}

// QKV: blocks 0..255 -> Q, 256..511 -> K, 512..767 -> Vt (A=Wv, B=x -> transposed out)
__global__ __launch_bounds__(256, 3) void qkv_gemm_k(
    const _Float16* __restrict__ xh, const _Float16* __restrict__ Wqh,
    const _Float16* __restrict__ Wkh, const _Float16* __restrict__ Wvh,
    const float* __restrict__ bq, const float* __restrict__ bk,
    const float* __restrict__ bv, _Float16* __restrict__ Qh,
    _Float16* __restrict__ Kh, _Float16* __restrict__ Vt)
{
  int id = (int)blockIdx.x;
  if (id < 512) {
    int t = id & 255;
    const _Float16* Bp = (id < 256) ? Wqh : Wkh;
    const float*    bp = (id < 256) ? bq : bk;
    _Float16*       Cp = (id < 256) ? Qh : Kh;
    gemm_tile(xh, Bp, bp, Cp, nullptr, (t >> 3) * 128, (t & 7) * 128, 1024, 0);
  } else {
    int t = id - 512;  // M=1024 (e), N=4096 (b*s)
    gemm_tile(Wvh, xh, bv, Vt, nullptr, (t >> 5) * 128, (t & 31) * 128, 4096, 1);
  }
}

__global__ __launch_bounds__(256, 3) void out_gemm_k(
    const _Float16* __restrict__ Oh, const _Float16* __restrict__ Woh,
    const float* __restrict__ bo, float* __restrict__ outp)
{
  int id = (int)blockIdx.x;
  gemm_tile(Oh, Woh, bo, nullptr, outp, (id >> 3) * 128, (id & 7) * 128, 1024, 2);
}

// ---------------- V repack: Vt[e][b*S+s] -> V2 PV-fragment layout ----------------
// V2 element (b,h,ksg,dt,lane,r) = V[k=16*ksg+4*(lane>>4)+r][e=h*64+dt*16+(lane&15)].
__global__ __launch_bounds__(256) void repack_v_k(const _Float16* __restrict__ Vt,
                                                  _Float16* __restrict__ V2) {
  const int tid = (int)threadIdx.x;
  const int kgi = (int)blockIdx.x;   // 16 k-groups of 128
  const int h = (int)blockIdx.y, b = (int)blockIdx.z;
  const int k0 = kgi * 128;
  __shared__ alignas(16) _Float16 Vl[64 * 128];  // [er][k] 16KB
#pragma unroll
  for (int i = 0; i < 4; ++i) {
    int s = tid + i * 256;
    int er = s >> 4, c = s & 15;   // logical chunk c^(er&15) -> physical chunk c
    GLD16(Vt + (size_t)(h * 64 + er) * 4096 + b * 2048 + k0 + ((c ^ (er & 15)) * 8),
          Vl + s * 8);
  }
  __syncthreads();
  const int lane = tid & 63, dtsub = tid >> 6;
  const int col = lane & 15, g = lane >> 4;
  const int er = dtsub * 16 + col;
  _Float16* out = V2 + ((((size_t)(b * 16 + h) * 128 + (k0 >> 4)) * 4 + dtsub) * 256) + lane * 4;
#pragma unroll
  for (int ks = 0; ks < 8; ++ks) {
    int cl = 2 * ks + (g >> 1);          // logical chunk of k-offset ks*16+4g
    int phys = cl ^ col;                 // er&15 == col
    hf4 v = *(const hf4*)&Vl[er * 128 + phys * 8 + (g & 1) * 4];
    *(hf4*)(out + (size_t)ks * 1024) = v;   // next ksg slice = +4*256 elems
  }
}

// ---------------- pass 1: QK stats -> C3 = 0.125*mx + ln(sum_h exp(...)) ----------------
// C3 fragment layout: C3[b][kt16][qt16][lane*4+r] (1KB coalesced wave transactions both
// sides). 4 waves/WG; wave wv owns k-rows [kt0+16wv,+16). Heads staged in PAIRS
// (contiguous 128-d slabs): Kt [64k][128d] dbuf -> 8 barrier iters, 4 MFMA per stage.
__global__ __launch_bounds__(256, 4) void qk_stats_k(
    const _Float16* __restrict__ Qh, const _Float16* __restrict__ Kh,
    float* __restrict__ C0, float* __restrict__ C1)
{
  const int tid = (int)threadIdx.x;
  const int lane = tid & 63, wv = tid >> 6;     // wv 0..3
  const int col = lane & 15, g = lane >> 4;
  const int id = (int)blockIdx.x;
  const int xcd = id & 7, j = id >> 3;          // j 0..1023
  const int b = xcd >> 2, qq = xcd & 3;
  const int kx = j >> 5, qyl = j & 31;          // kx outer (32 x 64k), qy inner
  const int q0 = (qq * 32 + qyl) * 16;
  const int kt0 = kx * 64;

  __shared__ alignas(16) _Float16 Kt[2][8192];  // [64k][128d] x2 = 32KB
  __shared__ alignas(16) _Float16 Qt[2][2048];  // [16q][128d] x2 = 8KB

  const _Float16* Kbase = Kh + (size_t)(b * 2048 + kt0) * 1024;
  const _Float16* Qbase = Qh + (size_t)(b * 2048 + q0) * 1024;

  // K buffer: 1024 x 16B slots (4/thread); Q: 256 slots (1/thread)
#define STG1(bufi, hp) {                                                      \
    _Pragma("unroll")                                                         \
    for (int i_ = 0; i_ < 4; ++i_) {                                          \
      int s_ = tid + i_ * 256, r_ = s_ >> 4, pc_ = s_ & 15;                   \
      GLD16(Kbase + (size_t)r_ * 1024 + (hp) * 128 + ((pc_ ^ (r_ & 15)) * 8), \
            &Kt[bufi][s_ * 8]);                                               \
    }                                                                         \
    { int r_ = tid >> 4, pc_ = tid & 15;                                      \
      GLD16(Qbase + (size_t)r_ * 1024 + (hp) * 128 + ((pc_ ^ r_) * 8),        \
            &Qt[bufi][tid * 8]); } }

  fx4 lg[16];
#pragma unroll
  for (int h = 0; h < 16; ++h) lg[h] = fx4{0.f, 0.f, 0.f, 0.f};

  STG1(0, 0);
  int buf = 0;
  const int krow = wv * 16 + col;
#pragma unroll
  for (int hp = 0; hp < 8; ++hp) {
    __syncthreads();
    if (hp < 7) STG1(buf ^ 1, hp + 1);
#pragma unroll
    for (int hh = 0; hh < 2; ++hh) {
      const int h = 2 * hp + hh;
      hf8 ka0 = *(const hf8*)&Kt[buf][krow * 128 + (((hh * 8 + 0 + g) ^ (krow & 15)) * 8)];
      hf8 ka1 = *(const hf8*)&Kt[buf][krow * 128 + (((hh * 8 + 4 + g) ^ (krow & 15)) * 8)];
      hf8 qa0 = *(const hf8*)&Qt[buf][col * 128 + (((hh * 8 + 0 + g) ^ col) * 8)];
      hf8 qa1 = *(const hf8*)&Qt[buf][col * 128 + (((hh * 8 + 4 + g) ^ col) * 8)];
      lg[h] = __builtin_amdgcn_mfma_f32_16x16x32_f16(ka0, qa0, lg[h], 0, 0, 0);
      lg[h] = __builtin_amdgcn_mfma_f32_16x16x32_f16(ka1, qa1, lg[h], 0, 0, 0);
    }
    buf ^= 1;
  }
#undef STG1

  fx4 mx = lg[0];
#pragma unroll
  for (int h = 1; h < 16; ++h)
#pragma unroll
    for (int r = 0; r < 4; ++r) mx[r] = fmaxf(mx[r], lg[h][r]);
  fx4 sm = fx4{0.f, 0.f, 0.f, 0.f};
#pragma unroll
  for (int h = 0; h < 16; ++h)
#pragma unroll
    for (int r = 0; r < 4; ++r) sm[r] += __expf((lg[h][r] - mx[r]) * 0.125f);
  fx4 C;
#pragma unroll
  for (int r = 0; r < 4; ++r) C[r] = mx[r] * 0.125f + __logf(sm[r]);

  float* Cb = b ? C1 : C0;
  const int ktp = kx * 4 + wv;        // kt16 index 0..127
  const int qt  = qq * 32 + qyl;      // qt16 index 0..127
  *(fx4*)(Cb + ((size_t)ktp * 128 + qt) * 256 + lane * 4) = C;
}

// ---------------- pass 2: per-head attn = exp(0.125*lg - C) store + PV ----------------
// One head, 64 q-rows per WG (8 waves, 4 q-subtiles). Wave wv reads ONLY its own 16
// K-rows -> K staging is PER-WAVE (own LDS region, dbuf, NO barrier). Q fragments
// hoisted to REGISTERS once (8 hf8 = 32 VGPRs; launch_bounds (512,2) since occupancy
// is LDS-bound at 2 WGs/CU anyway) -> hot loop has no Q ds_reads. attn tile exchange
// (ssth) f16 + double-buffered -> ONE barrier per chunk. cc via coalesced fx4 from
// C3; V2 B-frags shared across 4 subtiles; stores nontemporal 512B-contiguous runs.
__global__ __launch_bounds__(512, 2) void pv_attn_k(
    const _Float16* __restrict__ Qh, const _Float16* __restrict__ Kh,
    const _Float16* __restrict__ V2, const float* __restrict__ C0,
    const float* __restrict__ C1, float* __restrict__ attnp,
    _Float16* __restrict__ Oh)
{
  const int tid = (int)threadIdx.x;
  const int lane = tid & 63, wv = tid >> 6;
  const int col = lane & 15, g = lane >> 4;
  const int id = (int)blockIdx.x;
  const int lin = (id & 7) * 128 + (id >> 3);   // XCD gets 128 consecutive lin
  const int b = lin >> 9, qt64 = (lin >> 4) & 31, h = lin & 15;  // h fastest
  const int q0 = qt64 * 64;

  __shared__ alignas(16) _Float16 Kt[2][8192];        // per-wave [wv][16k][64d] x2 = 32KB
  __shared__ alignas(16) _Float16 Qt[4096];           // [64q][64d] = 8KB
  __shared__ alignas(16) _Float16 ssth[2][4][16][136];// dbuf f16 attn tiles = 34.8KB

  const _Float16* Kbh = Kh + (size_t)(b * 2048) * 1024 + h * 64;
  const float*    Cb  = b ? C1 : C0;

  // per-wave K staging: wave stages its own rows [kc*128+wv*16, +16), 2 GLD16s
#define STGKW(bufi, kc) {                                                       \
    int s0_ = lane, s1_ = lane + 64;                                            \
    GLD16(Kbh + (size_t)((kc) * 128 + wv * 16 + (s0_ >> 3)) * 1024 +            \
              ((s0_ & 7) ^ ((s0_ >> 3) & 7)) * 8,                               \
          &Kt[bufi][wv * 1024 + s0_ * 8]);                                      \
    GLD16(Kbh + (size_t)((kc) * 128 + wv * 16 + (s1_ >> 3)) * 1024 +            \
              ((s1_ & 7) ^ ((s1_ >> 3) & 7)) * 8,                               \
          &Kt[bufi][wv * 1024 + s1_ * 8]); }

  // stage Q once: [64 q][64 d] = 512 x 16B (1/thread)
  {
    int qr_ = tid >> 3, qc_ = tid & 7;
    GLD16(Qh + (size_t)(b * 2048 + q0 + qr_) * 1024 + h * 64 + (qc_ ^ (qr_ & 7)) * 8,
          &Qt[tid * 8]);
  }
  STGKW(0, 0);
  __syncthreads();   // Q + first K visible (barrier implies vmcnt drain)

  // hoist Q fragments to registers: 4 subtiles x 2 hf8 = 32 VGPRs, loop-invariant
  hf8 qf[4][2];
#pragma unroll
  for (int t = 0; t < 4; ++t) {
    const int qrow = t * 16 + col;
    qf[t][0] = *(const hf8*)&Qt[qrow * 64 + ((0 + g) ^ (qrow & 7)) * 8];
    qf[t][1] = *(const hf8*)&Qt[qrow * 64 + ((4 + g) ^ (qrow & 7)) * 8];
  }

  fx4 acc[4][4];
#pragma unroll
  for (int t = 0; t < 4; ++t)
#pragma unroll
    for (int dt = 0; dt < 4; ++dt) acc[t][dt] = fx4{0.f, 0.f, 0.f, 0.f};

  int buf = 0;
  const int srow = 2 * wv + (lane >> 5);   // store-phase row (0..15)
  const int sks  = (lane & 31) * 4;        // store-phase k offset (0..124)
  float* attnbase = attnp + (size_t)((b * 16 + h) * 2048 + q0) * 2048;
  const _Float16* v2h = V2 + (size_t)(b * 16 + h) * 131072 + lane * 4;

  for (int kc = 0; kc < 16; ++kc) {
    // early: read own K frags for this chunk (staged last chunk; long since landed)
    hf8 ka0 = *(const hf8*)&Kt[buf][wv * 1024 + col * 64 + ((0 + g) ^ (col & 7)) * 8];
    hf8 ka1 = *(const hf8*)&Kt[buf][wv * 1024 + col * 64 + ((4 + g) ^ (col & 7)) * 8];
    // issue next chunk's own-K stage; no barrier — region is private to this wave
    if (kc < 15) STGKW(buf ^ 1, kc + 1);

    const int ksg = kc * 8 + wv;
    const _Float16* v2b = v2h + (size_t)ksg * 1024;
    hf4 vb[4];
#pragma unroll
    for (int dt = 0; dt < 4; ++dt) vb[dt] = *(const hf4*)(v2b + dt * 256);

#pragma unroll
    for (int t = 0; t < 4; ++t) {
      fx4 lg = fx4{0.f, 0.f, 0.f, 0.f};
      lg = __builtin_amdgcn_mfma_f32_16x16x32_f16(ka0, qf[t][0], lg, 0, 0, 0);
      lg = __builtin_amdgcn_mfma_f32_16x16x32_f16(ka1, qf[t][1], lg, 0, 0, 0);

      // one fully-coalesced fx4 per wave: C3[ksg][qt64*4+t][lane*4..]
      fx4 cc = *(const fx4*)(Cb + ((size_t)ksg * 128 + qt64 * 4 + t) * 256 + lane * 4);
      fx4 av;
#pragma unroll
      for (int r = 0; r < 4; ++r) av[r] = __expf(lg[r] * 0.125f - cc[r]);

      hf4 pa = {(_Float16)av[0], (_Float16)av[1], (_Float16)av[2], (_Float16)av[3]};
#pragma unroll
      for (int dt = 0; dt < 4; ++dt)
        acc[t][dt] = __builtin_amdgcn_mfma_f32_16x16x16f16(pa, vb[dt], acc[t][dt], 0, 0, 0);

      *(hf4*)&ssth[kc & 1][t][col][wv * 16 + 4 * g] = pa;
    }
    __syncthreads();  // the ONLY barrier per chunk: publish ssth[kc&1]

    // store phase: f16 tile -> f32 nontemporal, 512B-contiguous runs per instr.
    // Next chunk writes ssth[(kc+1)&1] (disjoint); ssth[kc&1] is rewritten only in
    // chunk kc+2, which every wave reaches after the NEXT barrier -> race-free.
#pragma unroll
    for (int t = 0; t < 4; ++t) {
      hf4 v = *(const hf4*)&ssth[kc & 1][t][srow][sks];
      fx4 val = {(float)v[0], (float)v[1], (float)v[2], (float)v[3]};
      __builtin_nontemporal_store(
          val, (fx4*)(attnbase + (size_t)(t * 16 + srow) * 2048 + kc * 128 + sks));
    }
    buf ^= 1;
  }
#undef STGKW

  // reduce 8 waves' partial O in LDS (reuse ssth as f32 scratch): Osum[64q][64e] 16KB
  float* Osum = (float*)&ssth[0][0][0][0];
  for (int w = 0; w < 8; ++w) {
    __syncthreads();
    if (wv == w) {
#pragma unroll
      for (int t = 0; t < 4; ++t)
#pragma unroll
        for (int dt = 0; dt < 4; ++dt)
#pragma unroll
          for (int r = 0; r < 4; ++r) {
            int idx = (t * 16 + 4 * g + r) * 64 + dt * 16 + col;
            Osum[idx] = (w == 0) ? acc[t][dt][r] : Osum[idx] + acc[t][dt][r];
          }
    }
  }
  __syncthreads();
#pragma unroll
  for (int it = 0; it < 2; ++it) {
    int s = tid + it * 512;               // 1024 slots: 64q x 16 e4-groups
    int q = s >> 4, e4 = (s & 15) * 4;
    hf4 o = {(_Float16)Osum[q * 64 + e4],     (_Float16)Osum[q * 64 + e4 + 1],
             (_Float16)Osum[q * 64 + e4 + 2], (_Float16)Osum[q * 64 + e4 + 3]};
    *(hf4*)(Oh + (size_t)(b * 2048 + q0 + q) * 1024 + h * 64 + e4) = o;
  }
}

// ---------------- launcher ----------------
extern "C" void kernel_launch(void* const* d_in, const int* in_sizes, int n_in,
                              void* d_out, int out_size, void* d_ws, size_t ws_size,
                              hipStream_t stream) {
  (void)in_sizes; (void)n_in; (void)out_size; (void)ws_size;
  const float* x  = (const float*)d_in[0];
  const float* Wq = (const float*)d_in[1];
  const float* bq = (const float*)d_in[2];
  const float* Wk = (const float*)d_in[3];
  const float* bk = (const float*)d_in[4];
  const float* Wv = (const float*)d_in[5];
  const float* bv = (const float*)d_in[6];
  const float* Wo = (const float*)d_in[7];
  const float* bo = (const float*)d_in[8];

  char* ws = (char*)d_ws;                           // layout (MiB offsets):
  _Float16* xh   = (_Float16*)(ws + (0ull  << 20)); // 0..8    x fp16 (dead after qkv)
  _Float16* V2   = (_Float16*)(ws + (0ull  << 20)); // 0..8    V2 pack (after qkv)
  _Float16* Wqh  = (_Float16*)(ws + (8ull  << 20)); // 8..10
  _Float16* Wkh  = (_Float16*)(ws + (10ull << 20)); // 10..12
  _Float16* Wvh  = (_Float16*)(ws + (12ull << 20)); // 12..14
  _Float16* Woh  = (_Float16*)(ws + (14ull << 20)); // 14..16
  _Float16* Qh   = (_Float16*)(ws + (16ull << 20)); // 16..24  Q fp16 [4096][1024]
  _Float16* Kh   = (_Float16*)(ws + (24ull << 20)); // 24..32  K fp16
  _Float16* Vt   = (_Float16*)(ws + (32ull << 20)); // 32..40  V^T fp16 [1024][4096]
  _Float16* Oh   = (_Float16*)(ws + (40ull << 20)); // 40..48  attn-out fp16 [4096][1024]
  float*    C1   = (float*)   (ws + (48ull << 20)); // 48..64  C3 stats b=1 (16 MiB)

  float* outp  = (float*)d_out;
  float* C0    = outp;               // C3 stats b=0 borrows outp (overwritten later)
  float* attnp = outp + 4194304ull;  // attn region [2][16][2048][2048] f32

  cvt_x_k<<<4096, 256, 0, stream>>>(x, xh);
  cvt_w_k<<<dim3(1024, 4), 256, 0, stream>>>(Wq, Wk, Wv, Wo, Wqh);
  qkv_gemm_k<<<768, 256, 0, stream>>>(xh, Wqh, Wkh, Wvh, bq, bk, bv, Qh, Kh, Vt);
  repack_v_k<<<dim3(16, 16, 2), 256, 0, stream>>>(Vt, V2);
  qk_stats_k<<<8192, 256, 0, stream>>>(Qh, Kh, C0, C1);
  pv_attn_k<<<1024, 512, 0, stream>>>(Qh, Kh, V2, C0, C1, attnp, Oh);
  out_gemm_k<<<256, 256, 0, stream>>>(Oh, Woh, bo, outp);
}

// Round 14
// 288.879 us; speedup vs baseline: 1.1108x; 1.1108x over previous
//
#include <hip/hip_runtime.h>

// fp16 vector types for MFMA fragments
typedef _Float16 hf2 __attribute__((ext_vector_type(2)));
typedef _Float16 hf4 __attribute__((ext_vector_type(4)));
typedef _Float16 hf8 __attribute__((ext_vector_type(8)));
typedef float    fx4 __attribute__((ext_vector_type(4)));

// async global->LDS, 16B per lane; LDS dest must be lane-linear (base + lane*16)
#define GLD16(gp, lp) __builtin_amdgcn_global_load_lds(                      \
    (const __attribute__((address_space(1))) void*)(gp),                     \
    (__attribute__((address_space(3))) void*)(lp), 16, 0, 0)

// ---------------- f32 -> f16 conversion ----------------
__global__ __launch_bounds__(256) void cvt_x_k(const float* __restrict__ s,
                                               _Float16* __restrict__ d) {
  size_t i = (size_t)blockIdx.x * 256 + threadIdx.x;  // grid 4096 -> 1,048,576 float4s
  float4 v = ((const float4*)s)[i];
  hf4 o = {(_Float16)v.x, (_Float16)v.y, (_Float16)v.z, (_Float16)v.w};
  *(hf4*)(d + 4 * i) = o;
}

__global__ __launch_bounds__(256) void cvt_w_k(const float* __restrict__ s0,
                                               const float* __restrict__ s1,
                                               const float* __restrict__ s2,
                                               const float* __restrict__ s3,
                                               _Float16* __restrict__ d) {
  const float* s = blockIdx.y == 0 ? s0 : blockIdx.y == 1 ? s1 : blockIdx.y == 2 ? s2 : s3;
  size_t i = (size_t)blockIdx.x * 256 + threadIdx.x;  // grid.x 1024 -> 262,144 float4s
  float4 v = ((const float4*)s)[i];
  hf4 o = {(_Float16)v.x, (_Float16)v.y, (_Float16)v.z, (_Float16)v.w};
  *(hf4*)(d + (size_t)blockIdx.y * 1048576 + 4 * i) = o;
}

// ---------------- 128x128 tile GEMM, C = A[M,1024] * B[N,1024]^T + bias ----------------
__device__ __forceinline__ void gemm_tile(
    const _Float16* __restrict__ A, const _Float16* __restrict__ B,
    const float* __restrict__ bias, _Float16* __restrict__ Ch,
    float* __restrict__ Cf, int m0, int n0, int ldc, int mode)
{
  __shared__ alignas(16) _Float16 Asm[2][128 * 32];
  __shared__ alignas(16) _Float16 Bsm[2][128 * 32];
  const int tid = (int)threadIdx.x;
  const int lane = tid & 63, wv = tid >> 6;
  const int col = lane & 15, g = lane >> 4;

  fx4 acc[2][8];
#pragma unroll
  for (int i = 0; i < 2; ++i)
#pragma unroll
    for (int j = 0; j < 8; ++j) acc[i][j] = fx4{0.f, 0.f, 0.f, 0.f};

  const int cp0 = tid, cp1 = tid + 256;
  const int row0 = cp0 >> 2, row1 = cp1 >> 2;
  const int ch0 = (cp0 & 3) ^ ((row0 >> 1) & 3);
  const int ch1 = (cp1 & 3) ^ ((row1 >> 1) & 3);
  const _Float16* a0 = A + (size_t)(m0 + row0) * 1024 + ch0 * 8;
  const _Float16* a1 = A + (size_t)(m0 + row1) * 1024 + ch1 * 8;
  const _Float16* b0 = B + (size_t)(n0 + row0) * 1024 + ch0 * 8;
  const _Float16* b1 = B + (size_t)(n0 + row1) * 1024 + ch1 * 8;

  int aoff[2], boff[8];
#pragma unroll
  for (int mi = 0; mi < 2; ++mi) {
    int row = wv * 32 + mi * 16 + col;
    aoff[mi] = (row * 4 + (g ^ ((row >> 1) & 3))) * 8;
  }
#pragma unroll
  for (int nj = 0; nj < 8; ++nj) {
    int row = nj * 16 + col;
    boff[nj] = (row * 4 + (g ^ ((row >> 1) & 3))) * 8;
  }

#define STAGE_T(bufi, kt) {                          \
    GLD16(a0 + (kt) * 32, &Asm[bufi][cp0 * 8]);      \
    GLD16(a1 + (kt) * 32, &Asm[bufi][cp1 * 8]);      \
    GLD16(b0 + (kt) * 32, &Bsm[bufi][cp0 * 8]);      \
    GLD16(b1 + (kt) * 32, &Bsm[bufi][cp1 * 8]); }

  STAGE_T(0, 0);
  int buf = 0;
  for (int kt = 0; kt < 32; ++kt) {
    __syncthreads();
    if (kt + 1 < 32) STAGE_T(buf ^ 1, kt + 1);
    hf8 af[2], bf[8];
#pragma unroll
    for (int mi = 0; mi < 2; ++mi) af[mi] = *(const hf8*)&Asm[buf][aoff[mi]];
#pragma unroll
    for (int nj = 0; nj < 8; ++nj) bf[nj] = *(const hf8*)&Bsm[buf][boff[nj]];
#pragma unroll
    for (int mi = 0; mi < 2; ++mi)
#pragma unroll
      for (int nj = 0; nj < 8; ++nj)
        acc[mi][nj] = __builtin_amdgcn_mfma_f32_16x16x32_f16(af[mi], bf[nj], acc[mi][nj], 0, 0, 0);
    buf ^= 1;
  }
#undef STAGE_T

  if (mode == 2) {
#pragma unroll
    for (int nj = 0; nj < 8; ++nj) {
      float bn = bias[n0 + nj * 16 + col];
#pragma unroll
      for (int mi = 0; mi < 2; ++mi)
#pragma unroll
        for (int r = 0; r < 4; ++r)
          Cf[(size_t)(m0 + wv * 32 + mi * 16 + 4 * g + r) * ldc + n0 + nj * 16 + col] =
              acc[mi][nj][r] + bn;
    }
  } else if (mode == 0) {
#pragma unroll
    for (int nj = 0; nj < 8; ++nj) {
      float bn = bias[n0 + nj * 16 + col];
#pragma unroll
      for (int mi = 0; mi < 2; ++mi)
#pragma unroll
        for (int r = 0; r < 4; ++r)
          Ch[(size_t)(m0 + wv * 32 + mi * 16 + 4 * g + r) * ldc + n0 + nj * 16 + col] =
              (_Float16)(acc[mi][nj][r] + bn);
    }
  } else {  // mode 1: bias over m
#pragma unroll
    for (int mi = 0; mi < 2; ++mi)
#pragma unroll
      for (int r = 0; r < 4; ++r) {
        float bm = bias[m0 + wv * 32 + mi * 16 + 4 * g + r];
#pragma unroll
        for (int nj = 0; nj < 8; ++nj)
          Ch[(size_t)(m0 + wv * 32 + mi * 16 + 4 * g + r) * ldc + n0 + nj * 16 + col] =
              (_Float16)(acc[mi][nj][r] + bm);
      }
  }
}

// QKV: blocks 0..255 -> Q, 256..511 -> K, 512..767 -> Vt (A=Wv, B=x -> transposed out)
__global__ __launch_bounds__(256, 3) void qkv_gemm_k(
    const _Float16* __restrict__ xh, const _Float16* __restrict__ Wqh,
    const _Float16* __restrict__ Wkh, const _Float16* __restrict__ Wvh,
    const float* __restrict__ bq, const float* __restrict__ bk,
    const float* __restrict__ bv, _Float16* __restrict__ Qh,
    _Float16* __restrict__ Kh, _Float16* __restrict__ Vt)
{
  int id = (int)blockIdx.x;
  if (id < 512) {
    int t = id & 255;
    const _Float16* Bp = (id < 256) ? Wqh : Wkh;
    const float*    bp = (id < 256) ? bq : bk;
    _Float16*       Cp = (id < 256) ? Qh : Kh;
    gemm_tile(xh, Bp, bp, Cp, nullptr, (t >> 3) * 128, (t & 7) * 128, 1024, 0);
  } else {
    int t = id - 512;  // M=1024 (e), N=4096 (b*s)
    gemm_tile(Wvh, xh, bv, Vt, nullptr, (t >> 5) * 128, (t & 31) * 128, 4096, 1);
  }
}

__global__ __launch_bounds__(256, 3) void out_gemm_k(
    const _Float16* __restrict__ Oh, const _Float16* __restrict__ Woh,
    const float* __restrict__ bo, float* __restrict__ outp)
{
  int id = (int)blockIdx.x;
  gemm_tile(Oh, Woh, bo, nullptr, outp, (id >> 3) * 128, (id & 7) * 128, 1024, 2);
}

// ---------------- V repack: Vt[e][b*S+s] -> V2 PV-fragment layout ----------------
// V2 element (b,h,ksg,dt,lane,r) = V[k=16*ksg+4*(lane>>4)+r][e=h*64+dt*16+(lane&15)].
__global__ __launch_bounds__(256) void repack_v_k(const _Float16* __restrict__ Vt,
                                                  _Float16* __restrict__ V2) {
  const int tid = (int)threadIdx.x;
  const int kgi = (int)blockIdx.x;   // 16 k-groups of 128
  const int h = (int)blockIdx.y, b = (int)blockIdx.z;
  const int k0 = kgi * 128;
  __shared__ alignas(16) _Float16 Vl[64 * 128];  // [er][k] 16KB
#pragma unroll
  for (int i = 0; i < 4; ++i) {
    int s = tid + i * 256;
    int er = s >> 4, c = s & 15;   // logical chunk c^(er&15) -> physical chunk c
    GLD16(Vt + (size_t)(h * 64 + er) * 4096 + b * 2048 + k0 + ((c ^ (er & 15)) * 8),
          Vl + s * 8);
  }
  __syncthreads();
  const int lane = tid & 63, dtsub = tid >> 6;
  const int col = lane & 15, g = lane >> 4;
  const int er = dtsub * 16 + col;
  _Float16* out = V2 + ((((size_t)(b * 16 + h) * 128 + (k0 >> 4)) * 4 + dtsub) * 256) + lane * 4;
#pragma unroll
  for (int ks = 0; ks < 8; ++ks) {
    int cl = 2 * ks + (g >> 1);          // logical chunk of k-offset ks*16+4g
    int phys = cl ^ col;                 // er&15 == col
    hf4 v = *(const hf4*)&Vl[er * 128 + phys * 8 + (g & 1) * 4];
    *(hf4*)(out + (size_t)ks * 1024) = v;   // next ksg slice = +4*256 elems
  }
}

// ---------------- pass 1: QK stats -> C3 = 0.125*mx + ln(sum_h exp(...)) ----------------
// C3 fragment layout: C3[b][kt16][qt16][lane*4+r] (1KB coalesced wave transactions both
// sides). 4 waves/WG; wave wv owns k-rows [kt0+16wv,+16). Heads staged in PAIRS
// (contiguous 128-d slabs): Kt [64k][128d] dbuf -> 8 barrier iters, 4 MFMA per stage.
__global__ __launch_bounds__(256, 4) void qk_stats_k(
    const _Float16* __restrict__ Qh, const _Float16* __restrict__ Kh,
    float* __restrict__ C0, float* __restrict__ C1)
{
  const int tid = (int)threadIdx.x;
  const int lane = tid & 63, wv = tid >> 6;     // wv 0..3
  const int col = lane & 15, g = lane >> 4;
  const int id = (int)blockIdx.x;
  const int xcd = id & 7, j = id >> 3;          // j 0..1023
  const int b = xcd >> 2, qq = xcd & 3;
  const int kx = j >> 5, qyl = j & 31;          // kx outer (32 x 64k), qy inner
  const int q0 = (qq * 32 + qyl) * 16;
  const int kt0 = kx * 64;

  __shared__ alignas(16) _Float16 Kt[2][8192];  // [64k][128d] x2 = 32KB
  __shared__ alignas(16) _Float16 Qt[2][2048];  // [16q][128d] x2 = 8KB

  const _Float16* Kbase = Kh + (size_t)(b * 2048 + kt0) * 1024;
  const _Float16* Qbase = Qh + (size_t)(b * 2048 + q0) * 1024;

  // K buffer: 1024 x 16B slots (4/thread); Q: 256 slots (1/thread)
#define STG1(bufi, hp) {                                                      \
    _Pragma("unroll")                                                         \
    for (int i_ = 0; i_ < 4; ++i_) {                                          \
      int s_ = tid + i_ * 256, r_ = s_ >> 4, pc_ = s_ & 15;                   \
      GLD16(Kbase + (size_t)r_ * 1024 + (hp) * 128 + ((pc_ ^ (r_ & 15)) * 8), \
            &Kt[bufi][s_ * 8]);                                               \
    }                                                                         \
    { int r_ = tid >> 4, pc_ = tid & 15;                                      \
      GLD16(Qbase + (size_t)r_ * 1024 + (hp) * 128 + ((pc_ ^ r_) * 8),        \
            &Qt[bufi][tid * 8]); } }

  fx4 lg[16];
#pragma unroll
  for (int h = 0; h < 16; ++h) lg[h] = fx4{0.f, 0.f, 0.f, 0.f};

  STG1(0, 0);
  int buf = 0;
  const int krow = wv * 16 + col;
#pragma unroll
  for (int hp = 0; hp < 8; ++hp) {
    __syncthreads();
    if (hp < 7) STG1(buf ^ 1, hp + 1);
#pragma unroll
    for (int hh = 0; hh < 2; ++hh) {
      const int h = 2 * hp + hh;
      hf8 ka0 = *(const hf8*)&Kt[buf][krow * 128 + (((hh * 8 + 0 + g) ^ (krow & 15)) * 8)];
      hf8 ka1 = *(const hf8*)&Kt[buf][krow * 128 + (((hh * 8 + 4 + g) ^ (krow & 15)) * 8)];
      hf8 qa0 = *(const hf8*)&Qt[buf][col * 128 + (((hh * 8 + 0 + g) ^ col) * 8)];
      hf8 qa1 = *(const hf8*)&Qt[buf][col * 128 + (((hh * 8 + 4 + g) ^ col) * 8)];
      lg[h] = __builtin_amdgcn_mfma_f32_16x16x32_f16(ka0, qa0, lg[h], 0, 0, 0);
      lg[h] = __builtin_amdgcn_mfma_f32_16x16x32_f16(ka1, qa1, lg[h], 0, 0, 0);
    }
    buf ^= 1;
  }
#undef STG1

  fx4 mx = lg[0];
#pragma unroll
  for (int h = 1; h < 16; ++h)
#pragma unroll
    for (int r = 0; r < 4; ++r) mx[r] = fmaxf(mx[r], lg[h][r]);
  fx4 sm = fx4{0.f, 0.f, 0.f, 0.f};
#pragma unroll
  for (int h = 0; h < 16; ++h)
#pragma unroll
    for (int r = 0; r < 4; ++r) sm[r] += __expf((lg[h][r] - mx[r]) * 0.125f);
  fx4 C;
#pragma unroll
  for (int r = 0; r < 4; ++r) C[r] = mx[r] * 0.125f + __logf(sm[r]);

  float* Cb = b ? C1 : C0;
  const int ktp = kx * 4 + wv;        // kt16 index 0..127
  const int qt  = qq * 32 + qyl;      // qt16 index 0..127
  *(fx4*)(Cb + ((size_t)ktp * 128 + qt) * 256 + lane * 4) = C;
}

// ---------------- pass 2: per-head attn = exp(0.125*lg - C) store + PV ----------------
// One head, 64 q-rows per WG (8 waves, 4 q-subtiles). Wave wv reads ONLY its own 16
// K-rows -> K staging is PER-WAVE (own LDS region, own GLD16s, dbuf, NO barrier);
// the early ds_read of the current buffer precedes the next stage issue so the
// compiler's vmcnt wait covers only last-chunk loads. attn tile exchange (ssth) is
// f16 (== the pa values PV consumes) and double-buffered -> exactly ONE barrier per
// chunk (16 total). cc via coalesced fx4 from C3; V2 B-frags shared across 4
// subtiles; stores nontemporal 512B-contiguous runs. LDS 74.8KB + VGPR<=128
// ((512,4) cap) -> 2 WGs/CU. [R13 lesson: (512,2)+Q-hoist pushed VGPR>128 ->
// occupancy fell to 1 WG/CU, -11%. Keep the cap.]
__global__ __launch_bounds__(512, 4) void pv_attn_k(
    const _Float16* __restrict__ Qh, const _Float16* __restrict__ Kh,
    const _Float16* __restrict__ V2, const float* __restrict__ C0,
    const float* __restrict__ C1, float* __restrict__ attnp,
    _Float16* __restrict__ Oh)
{
  const int tid = (int)threadIdx.x;
  const int lane = tid & 63, wv = tid >> 6;
  const int col = lane & 15, g = lane >> 4;
  const int id = (int)blockIdx.x;
  const int lin = (id & 7) * 128 + (id >> 3);   // XCD gets 128 consecutive lin
  const int b = lin >> 9, qt64 = (lin >> 4) & 31, h = lin & 15;  // h fastest
  const int q0 = qt64 * 64;

  __shared__ alignas(16) _Float16 Kt[2][8192];        // per-wave [wv][16k][64d] x2 = 32KB
  __shared__ alignas(16) _Float16 Qt[4096];           // [64q][64d] = 8KB
  __shared__ alignas(16) _Float16 ssth[2][4][16][136];// dbuf f16 attn tiles = 34.8KB

  const _Float16* Kbh = Kh + (size_t)(b * 2048) * 1024 + h * 64;
  const float*    Cb  = b ? C1 : C0;

  // per-wave K staging: wave stages its own rows [kc*128+wv*16, +16), 2 GLD16s
#define STGKW(bufi, kc) {                                                       \
    int s0_ = lane, s1_ = lane + 64;                                            \
    GLD16(Kbh + (size_t)((kc) * 128 + wv * 16 + (s0_ >> 3)) * 1024 +            \
              ((s0_ & 7) ^ ((s0_ >> 3) & 7)) * 8,                               \
          &Kt[bufi][wv * 1024 + s0_ * 8]);                                      \
    GLD16(Kbh + (size_t)((kc) * 128 + wv * 16 + (s1_ >> 3)) * 1024 +            \
              ((s1_ & 7) ^ ((s1_ >> 3) & 7)) * 8,                               \
          &Kt[bufi][wv * 1024 + s1_ * 8]); }

  // stage Q once: [64 q][64 d] = 512 x 16B (1/thread)
  {
    int qr_ = tid >> 3, qc_ = tid & 7;
    GLD16(Qh + (size_t)(b * 2048 + q0 + qr_) * 1024 + h * 64 + (qc_ ^ (qr_ & 7)) * 8,
          &Qt[tid * 8]);
  }
  STGKW(0, 0);
  __syncthreads();   // Q + first K visible (barrier implies vmcnt drain)

  fx4 acc[4][4];
#pragma unroll
  for (int t = 0; t < 4; ++t)
#pragma unroll
    for (int dt = 0; dt < 4; ++dt) acc[t][dt] = fx4{0.f, 0.f, 0.f, 0.f};

  int buf = 0;
  const int srow = 2 * wv + (lane >> 5);   // store-phase row (0..15)
  const int sks  = (lane & 31) * 4;        // store-phase k offset (0..124)
  float* attnbase = attnp + (size_t)((b * 16 + h) * 2048 + q0) * 2048;
  const _Float16* v2h = V2 + (size_t)(b * 16 + h) * 131072 + lane * 4;

  for (int kc = 0; kc < 16; ++kc) {
    // early: read own K frags for this chunk (staged last chunk; long since landed)
    hf8 ka0 = *(const hf8*)&Kt[buf][wv * 1024 + col * 64 + ((0 + g) ^ (col & 7)) * 8];
    hf8 ka1 = *(const hf8*)&Kt[buf][wv * 1024 + col * 64 + ((4 + g) ^ (col & 7)) * 8];
    // issue next chunk's own-K stage; no barrier — region is private to this wave
    if (kc < 15) STGKW(buf ^ 1, kc + 1);

    const int ksg = kc * 8 + wv;
    const _Float16* v2b = v2h + (size_t)ksg * 1024;
    hf4 vb[4];
#pragma unroll
    for (int dt = 0; dt < 4; ++dt) vb[dt] = *(const hf4*)(v2b + dt * 256);

#pragma unroll
    for (int t = 0; t < 4; ++t) {
      const int qrow = t * 16 + col;
      hf8 qa0 = *(const hf8*)&Qt[qrow * 64 + ((0 + g) ^ (qrow & 7)) * 8];
      hf8 qa1 = *(const hf8*)&Qt[qrow * 64 + ((4 + g) ^ (qrow & 7)) * 8];
      fx4 lg = fx4{0.f, 0.f, 0.f, 0.f};
      lg = __builtin_amdgcn_mfma_f32_16x16x32_f16(ka0, qa0, lg, 0, 0, 0);
      lg = __builtin_amdgcn_mfma_f32_16x16x32_f16(ka1, qa1, lg, 0, 0, 0);

      // one fully-coalesced fx4 per wave: C3[ksg][qt64*4+t][lane*4..]
      fx4 cc = *(const fx4*)(Cb + ((size_t)ksg * 128 + qt64 * 4 + t) * 256 + lane * 4);
      fx4 av;
#pragma unroll
      for (int r = 0; r < 4; ++r) av[r] = __expf(lg[r] * 0.125f - cc[r]);

      hf4 pa = {(_Float16)av[0], (_Float16)av[1], (_Float16)av[2], (_Float16)av[3]};
#pragma unroll
      for (int dt = 0; dt < 4; ++dt)
        acc[t][dt] = __builtin_amdgcn_mfma_f32_16x16x16f16(pa, vb[dt], acc[t][dt], 0, 0, 0);

      *(hf4*)&ssth[kc & 1][t][col][wv * 16 + 4 * g] = pa;
    }
    __syncthreads();  // the ONLY barrier per chunk: publish ssth[kc&1]

    // store phase: f16 tile -> f32 nontemporal, 512B-contiguous runs per instr.
    // Next chunk writes ssth[(kc+1)&1] (disjoint); ssth[kc&1] is rewritten only in
    // chunk kc+2, which every wave reaches after the NEXT barrier -> race-free.
#pragma unroll
    for (int t = 0; t < 4; ++t) {
      hf4 v = *(const hf4*)&ssth[kc & 1][t][srow][sks];
      fx4 val = {(float)v[0], (float)v[1], (float)v[2], (float)v[3]};
      __builtin_nontemporal_store(
          val, (fx4*)(attnbase + (size_t)(t * 16 + srow) * 2048 + kc * 128 + sks));
    }
    buf ^= 1;
  }
#undef STGKW

  // reduce 8 waves' partial O in LDS (reuse ssth as f32 scratch): Osum[64q][64e] 16KB
  float* Osum = (float*)&ssth[0][0][0][0];
  for (int w = 0; w < 8; ++w) {
    __syncthreads();
    if (wv == w) {
#pragma unroll
      for (int t = 0; t < 4; ++t)
#pragma unroll
        for (int dt = 0; dt < 4; ++dt)
#pragma unroll
          for (int r = 0; r < 4; ++r) {
            int idx = (t * 16 + 4 * g + r) * 64 + dt * 16 + col;
            Osum[idx] = (w == 0) ? acc[t][dt][r] : Osum[idx] + acc[t][dt][r];
          }
    }
  }
  __syncthreads();
#pragma unroll
  for (int it = 0; it < 2; ++it) {
    int s = tid + it * 512;               // 1024 slots: 64q x 16 e4-groups
    int q = s >> 4, e4 = (s & 15) * 4;
    hf4 o = {(_Float16)Osum[q * 64 + e4],     (_Float16)Osum[q * 64 + e4 + 1],
             (_Float16)Osum[q * 64 + e4 + 2], (_Float16)Osum[q * 64 + e4 + 3]};
    *(hf4*)(Oh + (size_t)(b * 2048 + q0 + q) * 1024 + h * 64 + e4) = o;
  }
}

// ---------------- launcher ----------------
extern "C" void kernel_launch(void* const* d_in, const int* in_sizes, int n_in,
                              void* d_out, int out_size, void* d_ws, size_t ws_size,
                              hipStream_t stream) {
  (void)in_sizes; (void)n_in; (void)out_size; (void)ws_size;
  const float* x  = (const float*)d_in[0];
  const float* Wq = (const float*)d_in[1];
  const float* bq = (const float*)d_in[2];
  const float* Wk = (const float*)d_in[3];
  const float* bk = (const float*)d_in[4];
  const float* Wv = (const float*)d_in[5];
  const float* bv = (const float*)d_in[6];
  const float* Wo = (const float*)d_in[7];
  const float* bo = (const float*)d_in[8];

  char* ws = (char*)d_ws;                           // layout (MiB offsets):
  _Float16* xh   = (_Float16*)(ws + (0ull  << 20)); // 0..8    x fp16 (dead after qkv)
  _Float16* V2   = (_Float16*)(ws + (0ull  << 20)); // 0..8    V2 pack (after qkv)
  _Float16* Wqh  = (_Float16*)(ws + (8ull  << 20)); // 8..10
  _Float16* Wkh  = (_Float16*)(ws + (10ull << 20)); // 10..12
  _Float16* Wvh  = (_Float16*)(ws + (12ull << 20)); // 12..14
  _Float16* Woh  = (_Float16*)(ws + (14ull << 20)); // 14..16
  _Float16* Qh   = (_Float16*)(ws + (16ull << 20)); // 16..24  Q fp16 [4096][1024]
  _Float16* Kh   = (_Float16*)(ws + (24ull << 20)); // 24..32  K fp16
  _Float16* Vt   = (_Float16*)(ws + (32ull << 20)); // 32..40  V^T fp16 [1024][4096]
  _Float16* Oh   = (_Float16*)(ws + (40ull << 20)); // 40..48  attn-out fp16 [4096][1024]
  float*    C1   = (float*)   (ws + (48ull << 20)); // 48..64  C3 stats b=1 (16 MiB)

  float* outp  = (float*)d_out;
  float* C0    = outp;               // C3 stats b=0 borrows outp (overwritten later)
  float* attnp = outp + 4194304ull;  // attn region [2][16][2048][2048] f32

  cvt_x_k<<<4096, 256, 0, stream>>>(x, xh);
  cvt_w_k<<<dim3(1024, 4), 256, 0, stream>>>(Wq, Wk, Wv, Wo, Wqh);
  qkv_gemm_k<<<768, 256, 0, stream>>>(xh, Wqh, Wkh, Wvh, bq, bk, bv, Qh, Kh, Vt);
  repack_v_k<<<dim3(16, 16, 2), 256, 0, stream>>>(Vt, V2);
  qk_stats_k<<<8192, 256, 0, stream>>>(Qh, Kh, C0, C1);
  pv_attn_k<<<1024, 512, 0, stream>>>(Qh, Kh, V2, C0, C1, attnp, Oh);
  out_gemm_k<<<256, 256, 0, stream>>>(Oh, Woh, bo, outp);
}